// Round 5
// baseline (808.900 us; speedup 1.0000x reference)
//
#include <hip/hip_runtime.h>
#include <hip/hip_bf16.h>
#include <hip/hip_cooperative_groups.h>

namespace cg = cooperative_groups;

// Problem constants: B=32, T=1024, D=512, K=3, L=max_len=4096.
#define BB 32
#define TT 1024
#define DD 512
#define LL 4096
#define KDIM 1536        // K*D (im2col reduction dim)
#define TP 1026          // padded T (+1 zero halo row each side)
#define ROWS (BB * TT)   // 32768
#define NT (KDIM / 32)   // 48 K-steps

typedef __attribute__((ext_vector_type(8))) short short8;
typedef __attribute__((ext_vector_type(8))) unsigned short ushort8;
typedef __attribute__((ext_vector_type(4))) float floatx4;

__device__ __forceinline__ unsigned short f2bf(float f) {
  unsigned int u = __builtin_bit_cast(unsigned int, f);
  u += 0x7FFF + ((u >> 16) & 1);
  return (unsigned short)(u >> 16);
}

#define GLOAD_LDS16(g, l)                                          \
  __builtin_amdgcn_global_load_lds(                                \
      (const __attribute__((address_space(1))) void*)(g),          \
      (__attribute__((address_space(3))) void*)(l), 16, 0, 0)

struct MegaArgs {
  const float* enc;
  const int* dur;
  const float* w1; const float* b1; const float* g1; const float* be1;
  const float* w2; const float* b2; const float* g2; const float* be2;
  const float* lw; const float* lb;
  unsigned short* enc_pad;
  unsigned short* h1_pad;
  unsigned short* wt1;
  unsigned short* wt2;
  float* expanded;
  float* dpo;
  int* cum;
  int* idx;
};

// ---------------------------------------------------------------------------
// Fused conv-as-GEMM + bias + ReLU + LayerNorm (+ linear head for LAYER==2).
// 128 rows x full N=512 per block; 8 waves (2Mx4N), acc[4][8]; BK=32;
// 3-deep LDS pipeline with counted vmcnt(5) (round-2 schedule, at the
// LDS-read/MFMA-balanced floor). Unchanged from round 2/4 except it is now
// a device function called from the cooperative mega-kernel.
// ---------------------------------------------------------------------------
template <int LAYER>
__device__ __forceinline__ void conv_ln_phase(
    const int bid, const int tid,
    const unsigned short* __restrict__ Xp, const unsigned short* __restrict__ Wt,
    const float* __restrict__ bias, const float* __restrict__ g,
    const float* __restrict__ be, const float* __restrict__ lw,
    const float* __restrict__ lb, unsigned short* __restrict__ Hp,
    float* __restrict__ dpo,
    unsigned short (&As)[3][128 * 32], unsigned short (&Bs)[3][512 * 32],
    float (&sS)[4][128], float (&sQ)[4][128],
    float (&muL)[128], float (&rsL)[128]) {
  const int lane = tid & 63;
  const int wid  = tid >> 6;           // 0..7
  const int srow = lane >> 2;          // staging row within 16
  const int gchunk = (lane & 3) ^ (srow & 3);
  const int frow = lane & 15;
  const int quad = lane >> 4;
  const int rdch = quad ^ (frow & 3);
  const int wm = (wid >> 2) * 64;      // M-half
  const int wn = (wid & 3) * 128;      // N-quarter
  const int wc = wid & 3;

  const int m0 = bid * 128;            // 128-row tiles never cross a batch
  const int bA = m0 >> 10;
  const int t0 = m0 & (TT - 1);

  const unsigned short* gA0 =
      Xp + (long)(bA * TP + t0 + wid * 16 + srow) * DD + gchunk * 8;
  const unsigned short* gB0 =
      Wt + (long)(wid * 16 + srow) * KDIM + gchunk * 8;

  floatx4 acc[4][8];
#pragma unroll
  for (int i = 0; i < 4; ++i)
#pragma unroll
    for (int j = 0; j < 8; ++j) acc[i][j] = (floatx4){0.f, 0.f, 0.f, 0.f};

#define STAGE(bi, kk)                                                         \
  do {                                                                        \
    const int tap_ = (kk) >> 9;                                               \
    const int c0_  = (kk) & 511;                                              \
    GLOAD_LDS16(gA0 + (long)tap_ * DD + c0_, &As[bi][(wid * 16) * 32]);       \
    GLOAD_LDS16(gB0 + (kk),                   &Bs[bi][(wid * 16) * 32]);      \
    GLOAD_LDS16(gB0 + (long)128 * KDIM + (kk), &Bs[bi][(128 + wid * 16) * 32]); \
    GLOAD_LDS16(gB0 + (long)256 * KDIM + (kk), &Bs[bi][(256 + wid * 16) * 32]); \
    GLOAD_LDS16(gB0 + (long)384 * KDIM + (kk), &Bs[bi][(384 + wid * 16) * 32]); \
  } while (0)

#define COMPUTE(bi)                                                           \
  do {                                                                        \
    short8 a_[4], b_[8];                                                      \
    _Pragma("unroll")                                                         \
    for (int i = 0; i < 4; ++i)                                               \
      a_[i] = *reinterpret_cast<const short8*>(                               \
          &As[bi][(wm + i * 16 + frow) * 32 + rdch * 8]);                     \
    _Pragma("unroll")                                                         \
    for (int j = 0; j < 8; ++j)                                               \
      b_[j] = *reinterpret_cast<const short8*>(                               \
          &Bs[bi][(wn + j * 16 + frow) * 32 + rdch * 8]);                     \
    _Pragma("unroll")                                                         \
    for (int i = 0; i < 4; ++i)                                               \
      _Pragma("unroll")                                                       \
      for (int j = 0; j < 8; ++j)                                             \
        acc[i][j] = __builtin_amdgcn_mfma_f32_16x16x32_bf16(                  \
            a_[i], b_[j], acc[i][j], 0, 0, 0);                                \
  } while (0)

  // Prologue: fill pipeline 2 deep (10 loads in flight).
  STAGE(0, 0);
  STAGE(1, 32);

  int cur = 0;  // t % 3
  int stg = 2;  // (t+2) % 3
  for (int t = 0; t < NT - 1; ++t) {
    asm volatile("s_waitcnt vmcnt(5)" ::: "memory");
    __builtin_amdgcn_s_barrier();
    __builtin_amdgcn_sched_barrier(0);
    if (t + 2 < NT) STAGE(stg, (t + 2) * 32);  // buffer last read at t-1
    COMPUTE(cur);
    cur = (cur == 2) ? 0 : cur + 1;
    stg = (stg == 2) ? 0 : stg + 1;
  }
  asm volatile("s_waitcnt vmcnt(0)" ::: "memory");
  __builtin_amdgcn_s_barrier();
  __builtin_amdgcn_sched_barrier(0);
  COMPUTE(cur);
#undef STAGE
#undef COMPUTE

  // --- bias + relu in place ---
  float bz[8];
#pragma unroll
  for (int j = 0; j < 8; ++j) bz[j] = bias[wn + j * 16 + frow];
#pragma unroll
  for (int i = 0; i < 4; ++i)
#pragma unroll
    for (int j = 0; j < 8; ++j)
#pragma unroll
      for (int r = 0; r < 4; ++r)
        acc[i][j][r] = fmaxf(acc[i][j][r] + bz[j], 0.f);

  // --- per-row LN stats: wave's 128 cols -> shfl over frow -> LDS ---
  float ps[16], pq[16];
#pragma unroll
  for (int i = 0; i < 4; ++i)
#pragma unroll
    for (int r = 0; r < 4; ++r) {
      float s = 0.f, q = 0.f;
#pragma unroll
      for (int j = 0; j < 8; ++j) {
        const float v = acc[i][j][r];
        s += v; q += v * v;
      }
      ps[i * 4 + r] = s; pq[i * 4 + r] = q;
    }
#pragma unroll
  for (int off = 1; off < 16; off <<= 1)
#pragma unroll
    for (int k = 0; k < 16; ++k) {
      ps[k] += __shfl_xor(ps[k], off);
      pq[k] += __shfl_xor(pq[k], off);
    }
  if (frow == 0) {
#pragma unroll
    for (int i = 0; i < 4; ++i)
#pragma unroll
      for (int r = 0; r < 4; ++r) {
        const int row = wm + i * 16 + quad * 4 + r;
        sS[wc][row] = ps[i * 4 + r];
        sQ[wc][row] = pq[i * 4 + r];
      }
  }
  __syncthreads();
  if (tid < 128) {
    const float s = sS[0][tid] + sS[1][tid] + sS[2][tid] + sS[3][tid];
    const float q = sQ[0][tid] + sQ[1][tid] + sQ[2][tid] + sQ[3][tid];
    const float mu = s * (1.f / DD);
    const float var = q * (1.f / DD) - mu * mu;
    muL[tid] = mu;
    rsL[tid] = rsqrtf(var + 1e-5f);
  }
  __syncthreads();

  float gg[8], bb[8];
#pragma unroll
  for (int j = 0; j < 8; ++j) {
    gg[j] = g[wn + j * 16 + frow];
    bb[j] = be[wn + j * 16 + frow];
  }

  if constexpr (LAYER == 1) {
    // LN -> bf16 -> LDS (stride 520) -> coalesced ushort8 store.
    unsigned short* Ls = &Bs[0][0];
    const int h = wm >> 6;
#pragma unroll
    for (int ph = 0; ph < 2; ++ph) {
      __syncthreads();
      if (h == ph) {
#pragma unroll
        for (int i = 0; i < 4; ++i)
#pragma unroll
          for (int r = 0; r < 4; ++r) {
            const int row = wm + i * 16 + quad * 4 + r;
            const float mu = muL[row];
            const float rs = rsL[row];
            const int lrow = row - ph * 64;
#pragma unroll
            for (int j = 0; j < 8; ++j) {
              const float v = (acc[i][j][r] - mu) * rs * gg[j] + bb[j];
              Ls[lrow * 520 + wn + j * 16 + frow] = f2bf(v);
            }
          }
      }
      __syncthreads();
      const long gbase = (long)(bA * TP + t0 + ph * 64 + 1) * DD;
#pragma unroll
      for (int it = 0; it < 8; ++it) {
        const int r2 = it * 8 + wid;
        const int cc = lane * 8;
        ushort8 val = *reinterpret_cast<const ushort8*>(&Ls[r2 * 520 + cc]);
        *reinterpret_cast<ushort8*>(&Hp[gbase + (long)r2 * DD + cc]) = val;
      }
    }
  } else {
    // LN -> dot with lin_w -> dpo.
    float ww[8];
#pragma unroll
    for (int j = 0; j < 8; ++j) ww[j] = lw[wn + j * 16 + frow];
#pragma unroll
    for (int i = 0; i < 4; ++i)
#pragma unroll
      for (int r = 0; r < 4; ++r) {
        const int row = wm + i * 16 + quad * 4 + r;
        const float mu = muL[row];
        const float rs = rsL[row];
        float d = 0.f;
#pragma unroll
        for (int j = 0; j < 8; ++j) {
          const float v = (acc[i][j][r] - mu) * rs * gg[j] + bb[j];
          d += v * ww[j];
        }
#pragma unroll
        for (int off = 1; off < 16; off <<= 1) d += __shfl_xor(d, off);
        if (frow == 0) sS[wc][row] = d;
      }
    __syncthreads();
    if (tid < 128)
      dpo[bid * 128 + tid] =
          sS[0][tid] + sS[1][tid] + sS[2][tid] + sS[3][tid] + lb[0];
  }
}

// ---------------------------------------------------------------------------
// Cooperative mega-kernel: the whole chain in ONE dispatch.
// Grid = 256 blocks x 512 threads, 1 block/CU (125 KB LDS) -> co-resident.
// Phases separated by __threadfence() (agent-scope: L2 writeback on gfx950)
// + grid.sync():
//   P0: enc pad/convert + h1 halos + weight transpose + cumsum + idx scatter
//   P1: GEMM1 + LN -> h1_pad
//   P2: GEMM2 + LN + linear -> dpo
//   P3: gather via idx table (NO binary-search dependency chain)
// ---------------------------------------------------------------------------
__global__ __launch_bounds__(512, 2) void mega_kernel(MegaArgs a) {
  __shared__ unsigned short As[3][128 * 32];  // 24 KB
  __shared__ unsigned short Bs[3][512 * 32];  // 96 KB
  __shared__ float sS[4][128];
  __shared__ float sQ[4][128];
  __shared__ float muL[128];
  __shared__ float rsL[128];

  const int bid = blockIdx.x;
  const int tid = threadIdx.x;
  cg::grid_group grid = cg::this_grid();

  // ---- Phase 0a: enc fp32 -> bf16 padded + zero halos (enc_pad AND h1_pad)
  {
    const long NCH = (long)BB * TP * 64;  // padded rows x 64 ushort8-chunks
    for (long c = bid * 512 + tid; c < NCH; c += 256 * 512) {
      const int row = (int)(c >> 6);
      const int col = ((int)c & 63) * 8;
      const int b  = row / TP;
      const int pr = row - b * TP;
      ushort8 v;
      if (pr == 0 || pr == TP - 1) {
        v = (ushort8)0;
        *reinterpret_cast<ushort8*>(a.h1_pad + (long)row * DD + col) = v;
      } else {
        const float* p = a.enc + ((long)(b * TT + pr - 1)) * DD + col;
        float4 x0 = *reinterpret_cast<const float4*>(p);
        float4 x1 = *reinterpret_cast<const float4*>(p + 4);
        v[0] = f2bf(x0.x); v[1] = f2bf(x0.y); v[2] = f2bf(x0.z); v[3] = f2bf(x0.w);
        v[4] = f2bf(x1.x); v[5] = f2bf(x1.y); v[6] = f2bf(x1.z); v[7] = f2bf(x1.w);
      }
      *reinterpret_cast<ushort8*>(a.enc_pad + (long)row * DD + col) = v;
    }
  }

  // ---- Phase 0b: weight transpose/convert, 384 64x64 tiles, LDS in Bs[0]
  {
    float* wtf = reinterpret_cast<float*>(&Bs[0][0]);  // 64x65 floats
    const int cc = tid & 63;
    const int r8 = tid >> 6;  // 0..7
    for (int w = bid; w < 384; w += 256) {
      const int z = (w >= 192);
      const int rem = w - z * 192;
      const int bx = rem & 7;
      const int by = rem >> 3;
      const float* W = z ? a.w2 : a.w1;
      unsigned short* Wt = z ? a.wt2 : a.wt1;
      const int n0 = bx * 64;
      const int k0 = by * 64;
      __syncthreads();
#pragma unroll
      for (int r = 0; r < 8; ++r)
        wtf[(r * 8 + r8) * 65 + cc] = W[(long)(k0 + r * 8 + r8) * DD + n0 + cc];
      __syncthreads();
#pragma unroll
      for (int r = 0; r < 8; ++r)
        Wt[(long)(n0 + r * 8 + r8) * KDIM + k0 + cc] =
            f2bf(wtf[cc * 65 + r * 8 + r8]);
    }
  }

  // ---- Phase 0c: cumsum (blocks 0..31, 512 thr x 2 elems) + idx scatter
  if (bid < 32) {
    int* scan = reinterpret_cast<int*>(&As[0][0]);
    int2 v = reinterpret_cast<const int2*>(a.dur + bid * TT)[tid];
    const int s0 = v.x, s1 = v.x + v.y;
    scan[tid] = s1;
    __syncthreads();
    for (int off = 1; off < 512; off <<= 1) {
      int x = (tid >= off) ? scan[tid - off] : 0;
      __syncthreads();
      scan[tid] += x;
      __syncthreads();
    }
    const int base = tid ? scan[tid - 1] : 0;
    reinterpret_cast<int2*>(a.cum + bid * TT)[tid] =
        make_int2(base + s0, base + s1);
    int* ib = a.idx + bid * LL;
    const int e0 = min(base + v.x, LL);
    for (int j = base; j < e0; ++j) ib[j] = 2 * tid;
    const int e1 = min(base + s1, LL);
    for (int j = base + v.x; j < e1; ++j) ib[j] = 2 * tid + 1;
  }

  __threadfence();
  grid.sync();

  // ---- Phase 1: GEMM1 + LN -> h1_pad
  conv_ln_phase<1>(bid, tid, a.enc_pad, a.wt1, a.b1, a.g1, a.be1,
                   nullptr, nullptr, a.h1_pad, nullptr,
                   As, Bs, sS, sQ, muL, rsL);

  __threadfence();
  grid.sync();

  // ---- Phase 2: GEMM2 + LN + linear -> dpo
  conv_ln_phase<2>(bid, tid, a.h1_pad, a.wt2, a.b2, a.g2, a.be2,
                   a.lw, a.lb, nullptr, a.dpo,
                   As, Bs, sS, sQ, muL, rsL);

  __threadfence();
  grid.sync();

  // ---- Phase 3: gather via idx table (plain stores; nt reverted)
  {
    const int tl = tid & 127;
    const int sub = tid >> 7;  // 0..3: frame-within-group
    for (int fi = bid; fi < ROWS; fi += 256) {
      const long gf = (long)fi * 4 + sub;
      const int b = (int)(gf >> 12);
      const int j = (int)(gf & (LL - 1));
      const int total = a.cum[b * TT + TT - 1];
      floatx4* o = reinterpret_cast<floatx4*>(a.expanded + gf * DD) + tl;
      if (j >= total) {
        *o = (floatx4){0.f, 0.f, 0.f, 0.f};
      } else {
        const int lo = a.idx[b * LL + j];
        const floatx4* src =
            reinterpret_cast<const floatx4*>(a.enc + ((long)b * TT + lo) * DD) +
            tl;
        *o = *src;
      }
    }
  }
}

// ---------------------------------------------------------------------------
extern "C" void kernel_launch(void* const* d_in, const int* in_sizes, int n_in,
                              void* d_out, int out_size, void* d_ws,
                              size_t ws_size, hipStream_t stream) {
  float* out = (float*)d_out;
  float* expanded = out;                       // [B, L, D] = 67,108,864 f
  float* dpo = out + (long)BB * LL * DD;       // [B, T]

  MegaArgs a;
  a.enc = (const float*)d_in[0];
  a.dur = (const int*)d_in[1];
  a.w1  = (const float*)d_in[2];
  a.b1  = (const float*)d_in[3];
  a.g1  = (const float*)d_in[4];
  a.be1 = (const float*)d_in[5];
  a.w2  = (const float*)d_in[6];
  a.b2  = (const float*)d_in[7];
  a.g2  = (const float*)d_in[8];
  a.be2 = (const float*)d_in[9];
  a.lw  = (const float*)d_in[10];
  a.lb  = (const float*)d_in[11];
  // Scratch carved out of the 256 MB expanded region (gather writes it last).
  a.enc_pad = (unsigned short*)(expanded);              // 33.6 MB
  a.h1_pad  = (unsigned short*)(expanded + 9000000);    // 33.6 MB
  a.wt1     = (unsigned short*)(expanded + 18000000);   // 1.5 MB
  a.wt2     = (unsigned short*)(expanded + 18400000);   // 1.5 MB
  a.expanded = expanded;
  a.dpo = dpo;
  a.cum = (int*)d_ws;                                   // 32768 ints
  a.idx = (int*)d_ws + ROWS;                            // 131072 ints

  void* params[] = {&a};
  hipLaunchCooperativeKernel((const void*)mega_kernel, dim3(256), dim3(512),
                             params, 0, stream);
}

// Round 6
// 513.704 us; speedup vs baseline: 1.5746x; 1.5746x over previous
//
#include <hip/hip_runtime.h>
#include <hip/hip_bf16.h>

// Problem constants: B=32, T=1024, D=512, K=3, L=max_len=4096.
#define BB 32
#define TT 1024
#define DD 512
#define LL 4096
#define KDIM 1536        // K*D (im2col reduction dim)
#define TP 1026          // padded T (+1 zero halo row each side)
#define ROWS (BB * TT)   // 32768
#define NT (KDIM / 32)   // 48 K-steps

typedef __attribute__((ext_vector_type(8))) short short8;
typedef __attribute__((ext_vector_type(8))) unsigned short ushort8;
typedef __attribute__((ext_vector_type(4))) float floatx4;

__device__ __forceinline__ unsigned short f2bf(float f) {
  unsigned int u = __builtin_bit_cast(unsigned int, f);
  u += 0x7FFF + ((u >> 16) & 1);
  return (unsigned short)(u >> 16);
}

#define GLOAD_LDS16(g, l)                                          \
  __builtin_amdgcn_global_load_lds(                                \
      (const __attribute__((address_space(1))) void*)(g),          \
      (__attribute__((address_space(3))) void*)(l), 16, 0, 0)

// ---------------------------------------------------------------------------
// Merged prep kernel:
//   blocks [0, PAD_BLKS)            : enc fp32 -> bf16 padded (zero halos)
//   blocks [PAD_BLKS, PAD_BLKS+16)  : zero halo rows of h1_pad
//   blocks [W0, W0+384)             : weights fp32 [1536][512] -> bf16
//                                     [512][1536], LDS-tiled transpose
//   blocks [C0, C0+32)              : per-batch cumsum + idx scatter table
//                                     (replaces gather's serial binary search)
// ---------------------------------------------------------------------------
#define PAD_BLKS ((BB * TP) / 4)   // 8208
#define W0 (PAD_BLKS + 16)         // 8224
#define C0 (W0 + 384)              // 8608
#define PREP_BLKS (C0 + 32)        // 8640

__global__ __launch_bounds__(256) void prep_kernel(
    const float* __restrict__ X, unsigned short* __restrict__ Xp,
    unsigned short* __restrict__ Hp,
    const float* __restrict__ W1, unsigned short* __restrict__ Wt1,
    const float* __restrict__ W2, unsigned short* __restrict__ Wt2,
    const int* __restrict__ dur, int* __restrict__ cum,
    int* __restrict__ idx) {
  __shared__ float tile[64][65];  // also aliased as the scan buffer
  const int tid = threadIdx.x;
  const int lane = tid & 63;

  if (blockIdx.x >= C0) {
    // ---- cumsum + idx scatter: one block per batch, 4 elems/thread ----
    int* ls = reinterpret_cast<int*>(tile);
    const int b = blockIdx.x - C0;
    int4 v = reinterpret_cast<const int4*>(dur + b * TT)[tid];
    const int s0 = v.x, s1 = s0 + v.y, s2 = s1 + v.z, s3 = s2 + v.w;
    ls[tid] = s3;
    __syncthreads();
    for (int off = 1; off < 256; off <<= 1) {
      int x = (tid >= off) ? ls[tid - off] : 0;
      __syncthreads();
      ls[tid] += x;
      __syncthreads();
    }
    const int base = tid ? ls[tid - 1] : 0;
    int4 o = {base + s0, base + s1, base + s2, base + s3};
    reinterpret_cast<int4*>(cum + b * TT)[tid] = o;
    // scatter src index for each output frame this thread's 4 durations own
    int* ib = idx + b * LL;
    int st = base;
    const int dv[4] = {v.x, v.y, v.z, v.w};
#pragma unroll
    for (int k = 0; k < 4; ++k) {
      const int e = min(st + dv[k], LL);
      for (int j = st; j < e; ++j) ib[j] = 4 * tid + k;
      st += dv[k];
    }
    return;
  }
  if (blockIdx.x >= W0) {
    // ---- weight transpose+convert ----
    const int w = blockIdx.x - W0;          // 0..383
    const int z = w / 192;
    const int rem = w - z * 192;
    const int bx = rem & 7;                 // 0..7  (DD/64)
    const int by = rem >> 3;                // 0..23 (KDIM/64)
    const float* W = z ? W2 : W1;
    unsigned short* Wt = z ? Wt2 : Wt1;
    const int n0 = bx * 64;
    const int k0 = by * 64;
    const int c = lane;
    const int r4 = tid >> 6;
#pragma unroll
    for (int r = 0; r < 16; ++r)
      tile[r * 4 + r4][c] = W[(long)(k0 + r * 4 + r4) * DD + n0 + c];
    __syncthreads();
#pragma unroll
    for (int r = 0; r < 16; ++r)
      Wt[(long)(n0 + r * 4 + r4) * KDIM + k0 + c] = f2bf(tile[c][r * 4 + r4]);
    return;
  }
  if (blockIdx.x >= PAD_BLKS) {
    // ---- h1_pad halo zeroing ----
    const int hid = (blockIdx.x - PAD_BLKS) * 4 + (tid >> 6);
    const int b = hid >> 1;
    const long r = (long)b * TP + ((hid & 1) ? (TP - 1) : 0);
    *reinterpret_cast<ushort8*>(Hp + r * DD + lane * 8) = (ushort8)0;
    return;
  }
  // ---- enc pad+convert ----
  const int row = blockIdx.x * 4 + (tid >> 6);
  const int b  = row / TP;
  const int pr = row - b * TP;
  ushort8* o = reinterpret_cast<ushort8*>(Xp + (long)row * DD + lane * 8);
  ushort8 v;
  if (pr == 0 || pr == TP - 1) {
    v = (ushort8)0;
  } else {
    const float* p = X + ((long)(b * TT + pr - 1)) * DD + lane * 8;
    float4 a = *reinterpret_cast<const float4*>(p);
    float4 c = *reinterpret_cast<const float4*>(p + 4);
    v[0] = f2bf(a.x); v[1] = f2bf(a.y); v[2] = f2bf(a.z); v[3] = f2bf(a.w);
    v[4] = f2bf(c.x); v[5] = f2bf(c.y); v[6] = f2bf(c.z); v[7] = f2bf(c.w);
  }
  *o = v;
}

// ---------------------------------------------------------------------------
// Fused conv-as-GEMM + bias + ReLU + LayerNorm (+ linear head for LAYER==2).
// ROUND-6 CHANGE: 1024 threads = 16 waves (2M x 8N), wave tile 64x64,
// acc[4][4] = 64 acc regs; __launch_bounds__(1024,4) caps regs at 128/wave
// -> 16 waves/CU resident (round-5 counters showed acc[4][8]=128 acc +
// ~116 VGPR > 128 total -> hard 8-wave/CU cap = Occupancy 23%, all pipes
// ~90% idle; this doubles wave-level latency hiding at the cost of +33%
// LDS fragment re-reads).
// K-loop: 3-deep LDS pipeline, counted vmcnt (per-wave load counts: waves
// 0-7 stage A+2B = 3/step -> vmcnt(3); waves 8-15 stage 2B -> vmcnt(2)).
// One s_barrier per K-step; sched_barrier(0) pins ds_reads after it.
// Full-N tile (128 x 512) -> LN reduces entirely in-block.
// ---------------------------------------------------------------------------
template <int LAYER>
__global__ __launch_bounds__(1024, 4) void fused_conv_ln_kernel(
    const unsigned short* __restrict__ Xp, const unsigned short* __restrict__ Wt,
    const float* __restrict__ bias, const float* __restrict__ g,
    const float* __restrict__ be, const float* __restrict__ lw,
    const float* __restrict__ lb, unsigned short* __restrict__ Hp,
    float* __restrict__ dpo) {
  __shared__ unsigned short As[3][128 * 32];  // 24 KB
  __shared__ unsigned short Bs[3][512 * 32];  // 96 KB (reused as Ls)
  __shared__ float sS[8][128];                // 4 KB
  __shared__ float sQ[8][128];                // 4 KB
  __shared__ float muL[128];
  __shared__ float rsL[128];

  const int tid  = threadIdx.x;
  const int lane = tid & 63;
  const int wid  = tid >> 6;           // 0..15
  const int srow = lane >> 2;          // staging row within 16
  const int gchunk = (lane & 3) ^ (srow & 3);
  const int frow = lane & 15;
  const int quad = lane >> 4;
  const int rdch = quad ^ (frow & 3);
  const int wm = (wid >> 3) * 64;      // M-strip (2)
  const int wn = (wid & 7) * 64;       // N-slice (8)
  const int wc = wid & 7;

  const int m0 = blockIdx.x * 128;     // 128-row tiles never cross a batch
  const int bA = m0 >> 10;
  const int t0 = m0 & (TT - 1);

  // staging roles: waves 0-7: 1 A-group (16 rows) + 2 B-groups (32 rows);
  // waves 8-15: 2 B-groups. Covers A rows 0..127, B rows 0..511.
  const unsigned short* gA0 =
      Xp + (long)(bA * TP + t0 + (wid & 7) * 16 + srow) * DD + gchunk * 8;
  const int bb0 = (wid < 8) ? wid * 32 : 256 + (wid - 8) * 32;  // B row base
  const unsigned short* gB0 =
      Wt + (long)(bb0 + srow) * KDIM + gchunk * 8;

  floatx4 acc[4][4];
#pragma unroll
  for (int i = 0; i < 4; ++i)
#pragma unroll
    for (int j = 0; j < 4; ++j) acc[i][j] = (floatx4){0.f, 0.f, 0.f, 0.f};

#define STAGE(bi, kk)                                                         \
  do {                                                                        \
    const int tap_ = (kk) >> 9;                                               \
    const int c0_  = (kk) & 511;                                              \
    if (wid < 8)                                                              \
      GLOAD_LDS16(gA0 + (long)tap_ * DD + c0_, &As[bi][(wid * 16) * 32]);     \
    GLOAD_LDS16(gB0 + (kk),                &Bs[bi][bb0 * 32]);                \
    GLOAD_LDS16(gB0 + (long)16 * KDIM + (kk), &Bs[bi][(bb0 + 16) * 32]);      \
  } while (0)

#define COMPUTE(bi)                                                           \
  do {                                                                        \
    short8 a_[4], b_[4];                                                      \
    _Pragma("unroll")                                                         \
    for (int i = 0; i < 4; ++i)                                               \
      a_[i] = *reinterpret_cast<const short8*>(                               \
          &As[bi][(wm + i * 16 + frow) * 32 + rdch * 8]);                     \
    _Pragma("unroll")                                                         \
    for (int j = 0; j < 4; ++j)                                               \
      b_[j] = *reinterpret_cast<const short8*>(                               \
          &Bs[bi][(wn + j * 16 + frow) * 32 + rdch * 8]);                     \
    _Pragma("unroll")                                                         \
    for (int i = 0; i < 4; ++i)                                               \
      _Pragma("unroll")                                                       \
      for (int j = 0; j < 4; ++j)                                             \
        acc[i][j] = __builtin_amdgcn_mfma_f32_16x16x32_bf16(                  \
            a_[i], b_[j], acc[i][j], 0, 0, 0);                                \
  } while (0)

  // Prologue: fill pipeline 2 deep.
  STAGE(0, 0);
  STAGE(1, 32);

  int cur = 0;  // t % 3
  int stg = 2;  // (t+2) % 3
  for (int t = 0; t < NT - 1; ++t) {
    // Wait tile t's loads (leave tile t+1's in flight across the barrier).
    if (wid < 8) asm volatile("s_waitcnt vmcnt(3)" ::: "memory");
    else         asm volatile("s_waitcnt vmcnt(2)" ::: "memory");
    __builtin_amdgcn_s_barrier();
    __builtin_amdgcn_sched_barrier(0);
    if (t + 2 < NT) STAGE(stg, (t + 2) * 32);  // buffer last read at t-1
    COMPUTE(cur);
    cur = (cur == 2) ? 0 : cur + 1;
    stg = (stg == 2) ? 0 : stg + 1;
  }
  asm volatile("s_waitcnt vmcnt(0)" ::: "memory");
  __builtin_amdgcn_s_barrier();
  __builtin_amdgcn_sched_barrier(0);
  COMPUTE(cur);
#undef STAGE
#undef COMPUTE

  // --- bias + relu in place ---
  float bz[4];
#pragma unroll
  for (int j = 0; j < 4; ++j) bz[j] = bias[wn + j * 16 + frow];
#pragma unroll
  for (int i = 0; i < 4; ++i)
#pragma unroll
    for (int j = 0; j < 4; ++j)
#pragma unroll
      for (int r = 0; r < 4; ++r)
        acc[i][j][r] = fmaxf(acc[i][j][r] + bz[j], 0.f);

  // --- per-row LN stats: wave's 64 cols -> shfl over frow -> LDS ---
  float ps[16], pq[16];
#pragma unroll
  for (int i = 0; i < 4; ++i)
#pragma unroll
    for (int r = 0; r < 4; ++r) {
      float s = 0.f, q = 0.f;
#pragma unroll
      for (int j = 0; j < 4; ++j) {
        const float v = acc[i][j][r];
        s += v; q += v * v;
      }
      ps[i * 4 + r] = s; pq[i * 4 + r] = q;
    }
#pragma unroll
  for (int off = 1; off < 16; off <<= 1)
#pragma unroll
    for (int k = 0; k < 16; ++k) {
      ps[k] += __shfl_xor(ps[k], off);
      pq[k] += __shfl_xor(pq[k], off);
    }
  if (frow == 0) {
#pragma unroll
    for (int i = 0; i < 4; ++i)
#pragma unroll
      for (int r = 0; r < 4; ++r) {
        const int row = wm + i * 16 + quad * 4 + r;
        sS[wc][row] = ps[i * 4 + r];
        sQ[wc][row] = pq[i * 4 + r];
      }
  }
  __syncthreads();
  if (tid < 128) {
    float s = 0.f, q = 0.f;
#pragma unroll
    for (int c = 0; c < 8; ++c) { s += sS[c][tid]; q += sQ[c][tid]; }
    const float mu = s * (1.f / DD);
    const float var = q * (1.f / DD) - mu * mu;
    muL[tid] = mu;
    rsL[tid] = rsqrtf(var + 1e-5f);
  }
  __syncthreads();

  float gg[4], bb[4];
#pragma unroll
  for (int j = 0; j < 4; ++j) {
    gg[j] = g[wn + j * 16 + frow];
    bb[j] = be[wn + j * 16 + frow];
  }

  if constexpr (LAYER == 1) {
    // LN -> bf16 -> LDS (stride 520) -> coalesced ushort8 store, 64-row halves.
    unsigned short* Ls = &Bs[0][0];  // 64*520*2 = 66.6 KB <= 96 KB
    const int h = wm >> 6;           // which half this wave's rows live in
#pragma unroll
    for (int ph = 0; ph < 2; ++ph) {
      __syncthreads();
      if (h == ph) {
#pragma unroll
        for (int i = 0; i < 4; ++i)
#pragma unroll
          for (int r = 0; r < 4; ++r) {
            const int row = wm + i * 16 + quad * 4 + r;
            const float mu = muL[row];
            const float rs = rsL[row];
            const int lrow = row - ph * 64;
#pragma unroll
            for (int j = 0; j < 4; ++j) {
              const float v = (acc[i][j][r] - mu) * rs * gg[j] + bb[j];
              Ls[lrow * 520 + wn + j * 16 + frow] = f2bf(v);
            }
          }
      }
      __syncthreads();
      const long gbase = (long)(bA * TP + t0 + ph * 64 + 1) * DD;
#pragma unroll
      for (int it = 0; it < 4; ++it) {
        const int r2 = it * 16 + wid;
        const int cc = lane * 8;
        ushort8 val = *reinterpret_cast<const ushort8*>(&Ls[r2 * 520 + cc]);
        *reinterpret_cast<ushort8*>(&Hp[gbase + (long)r2 * DD + cc]) = val;
      }
    }
  } else {
    // LN -> dot with lin_w -> dpo.
    float ww[4];
#pragma unroll
    for (int j = 0; j < 4; ++j) ww[j] = lw[wn + j * 16 + frow];
#pragma unroll
    for (int i = 0; i < 4; ++i)
#pragma unroll
      for (int r = 0; r < 4; ++r) {
        const int row = wm + i * 16 + quad * 4 + r;
        const float mu = muL[row];
        const float rs = rsL[row];
        float d = 0.f;
#pragma unroll
        for (int j = 0; j < 4; ++j) {
          const float v = (acc[i][j][r] - mu) * rs * gg[j] + bb[j];
          d += v * ww[j];
        }
#pragma unroll
        for (int off = 1; off < 16; off <<= 1) d += __shfl_xor(d, off);
        if (frow == 0) sS[wc][row] = d;  // reuse sS (stat reads done)
      }
    __syncthreads();
    if (tid < 128) {
      float s = lb[0];
#pragma unroll
      for (int c = 0; c < 8; ++c) s += sS[c][tid];
      dpo[blockIdx.x * 128 + tid] = s;
    }
  }
}

// ---------------------------------------------------------------------------
// Gather/expand: 512-thread blocks, 4 frames/block, full-occupancy grid.
// idx-table lookup (no serial binary-search chain); plain float4 stores
// (nt stores regressed in round 4 -> reverted).
// ---------------------------------------------------------------------------
__global__ __launch_bounds__(512) void gather_kernel(
    const float* __restrict__ X, const int* __restrict__ cum,
    const int* __restrict__ idx, float* __restrict__ out) {
  const long gf = (long)blockIdx.x * 4 + (threadIdx.x >> 7);
  const int tl = threadIdx.x & 127;
  const int b = (int)(gf >> 12);
  const int j = (int)(gf & (LL - 1));
  const int total = cum[b * TT + TT - 1];
  floatx4* o = reinterpret_cast<floatx4*>(out + gf * DD) + tl;
  if (j >= total) {
    *o = (floatx4){0.f, 0.f, 0.f, 0.f};
    return;
  }
  const int lo = idx[b * LL + j];
  const floatx4* src =
      reinterpret_cast<const floatx4*>(X + ((long)b * TT + lo) * DD) + tl;
  *o = *src;
}

// ---------------------------------------------------------------------------
extern "C" void kernel_launch(void* const* d_in, const int* in_sizes, int n_in,
                              void* d_out, int out_size, void* d_ws,
                              size_t ws_size, hipStream_t stream) {
  const float* enc = (const float*)d_in[0];
  const int* dur   = (const int*)d_in[1];
  const float* w1  = (const float*)d_in[2];
  const float* b1  = (const float*)d_in[3];
  const float* g1  = (const float*)d_in[4];
  const float* be1 = (const float*)d_in[5];
  const float* w2  = (const float*)d_in[6];
  const float* b2  = (const float*)d_in[7];
  const float* g2  = (const float*)d_in[8];
  const float* be2 = (const float*)d_in[9];
  const float* lw  = (const float*)d_in[10];
  const float* lb  = (const float*)d_in[11];

  float* out = (float*)d_out;
  float* expanded = out;                       // [B, L, D] = 67,108,864 f
  float* dpo = out + (long)BB * LL * DD;       // [B, T]

  // Scratch carved out of the 256 MB expanded region (gather writes it last).
  unsigned short* enc_pad = (unsigned short*)(expanded);              // 33.6 MB
  unsigned short* h1_pad  = (unsigned short*)(expanded + 9000000);    // 33.6 MB
  unsigned short* wt1     = (unsigned short*)(expanded + 18000000);   // 1.5 MB
  unsigned short* wt2     = (unsigned short*)(expanded + 18400000);   // 1.5 MB
  int* cum = (int*)d_ws;                        // 32768 ints
  int* idx = (int*)d_ws + ROWS;                 // 131072 ints

  prep_kernel<<<PREP_BLKS, 256, 0, stream>>>(enc, enc_pad, h1_pad, w1, wt1,
                                             w2, wt2, dur, cum, idx);

  fused_conv_ln_kernel<1><<<ROWS / 128, 1024, 0, stream>>>(
      enc_pad, wt1, b1, g1, be1, nullptr, nullptr, h1_pad, nullptr);
  fused_conv_ln_kernel<2><<<ROWS / 128, 1024, 0, stream>>>(
      h1_pad, wt2, b2, g2, be2, lw, lb, nullptr, dpo);

  gather_kernel<<<BB * LL / 4, 512, 0, stream>>>(enc, cum, idx, expanded);
}